// Round 1
// baseline (1207.184 us; speedup 1.0000x reference)
//
#include <hip/hip_runtime.h>
#include <math.h>

#define BB   256
#define CC   768
#define HHX  24
#define WWX  24
#define HWX  576      // H*W
#define EDIM 2304     // 3*C
#define NIMG 2

// ---------------------------------------------------------------------------
// k1: per-(img,b) channel-sum heatmap. hm[blk][t] = sum_c feat[b,c,t]
// (division by C omitted: monotonic, does not change masks)
__global__ void k1_hm(const float* __restrict__ f1, const float* __restrict__ f2,
                      float* __restrict__ hm) {
    int blk = blockIdx.x;            // 0..511  (img*256 + b)
    int img = blk >> 8;
    int b   = blk & 255;
    const float* base = ((img == 0) ? f1 : f2) + (size_t)b * CC * HWX;
    int t = threadIdx.x;             // 0..575
    float acc = 0.f;
    #pragma unroll 8
    for (int c = 0; c < CC; ++c)
        acc += base[(size_t)c * HWX + t];
    hm[(size_t)blk * HWX + t] = acc;
}

// ---------------------------------------------------------------------------
// k2: 3x3 border-clipped local max/min masks (+corner exclusion) and counts.
__global__ void k2_mask(const float* __restrict__ hm, float* __restrict__ mmax,
                        float* __restrict__ mmin, float* __restrict__ cnt) {
    int blk = blockIdx.x;            // (img,b)
    int t = threadIdx.x;             // 0..575
    __shared__ float sh[HWX];
    __shared__ int c0, c1;
    if (t == 0) { c0 = 0; c1 = 0; }
    float v = hm[(size_t)blk * HWX + t];
    sh[t] = v;
    __syncthreads();

    int h = t / WWX, w = t % WWX;
    float mx = -__builtin_inff(), mn = __builtin_inff();
    #pragma unroll
    for (int dh = -1; dh <= 1; ++dh) {
        int hh = h + dh;
        if (hh < 0 || hh >= HHX) continue;
        #pragma unroll
        for (int dw = -1; dw <= 1; ++dw) {
            int ww = w + dw;
            if (ww < 0 || ww >= WWX) continue;
            float u = sh[hh * WWX + ww];
            mx = fmaxf(mx, u);
            mn = fminf(mn, u);
        }
    }
    bool corner = (t == 0) || (t == WWX - 1) || (t == (HHX - 1) * WWX) || (t == HWX - 1);
    bool ismax = (v >= mx) && !corner;
    bool ismin = (v <= mn) && !corner;
    mmax[(size_t)blk * HWX + t] = ismax ? 1.f : 0.f;
    mmin[(size_t)blk * HWX + t] = ismin ? 1.f : 0.f;
    if (ismax) atomicAdd(&c0, 1);
    if (ismin) atomicAdd(&c1, 1);
    __syncthreads();
    if (t == 0) {
        cnt[blk * 2 + 0] = (float)c0;
        cnt[blk * 2 + 1] = (float)c1;
    }
}

// ---------------------------------------------------------------------------
// k3: pooled raw sums per (img,b,c): masked-max sum, masked-min sum, full sum.
// Block per (img,b), one wave per channel slice, masks cached in registers.
// Output layout "e-layout": sums[blk][c]=max, [CC+c]=min, [2*CC+c]=gap.
__global__ void k3_sums(const float* __restrict__ f1, const float* __restrict__ f2,
                        const float* __restrict__ mmax, const float* __restrict__ mmin,
                        float* __restrict__ sums) {
    int blk = blockIdx.x;            // (img,b)
    int img = blk >> 8, b = blk & 255;
    const float* base = ((img == 0) ? f1 : f2) + (size_t)b * CC * HWX;
    int lane = threadIdx.x & 63;
    int wv   = threadIdx.x >> 6;     // 0..3

    float mm[9], mn[9];
    #pragma unroll
    for (int j = 0; j < 9; ++j) {
        mm[j] = mmax[(size_t)blk * HWX + lane + 64 * j];
        mn[j] = mmin[(size_t)blk * HWX + lane + 64 * j];
    }
    float* out = sums + (size_t)blk * EDIM;

    for (int c = wv; c < CC; c += 4) {
        const float* p = base + (size_t)c * HWX;
        float s0 = 0.f, s1 = 0.f, s2 = 0.f;
        #pragma unroll
        for (int j = 0; j < 9; ++j) {
            float v = p[lane + 64 * j];
            s0 += v;
            s1 = fmaf(v, mm[j], s1);
            s2 = fmaf(v, mn[j], s2);
        }
        #pragma unroll
        for (int off = 32; off; off >>= 1) {
            s0 += __shfl_down(s0, off, 64);
            s1 += __shfl_down(s1, off, 64);
            s2 += __shfl_down(s2, off, 64);
        }
        if (lane == 0) {
            out[c]          = s1;
            out[CC + c]     = s2;
            out[2 * CC + c] = s0;
        }
    }
}

// ---------------------------------------------------------------------------
// k4: divide by counts / HW, L2-normalize each (img,b) row of 2304, and also
// write transposed copy of normalized e2 for coalesced GEMM reads.
__global__ void k4_norm(float* __restrict__ sums, const float* __restrict__ cnt,
                        float* __restrict__ e2t) {
    int blk = blockIdx.x;            // (img,b)
    int img = blk >> 8, b = blk & 255;
    int t = threadIdx.x;             // 0..255
    float invmax = 1.f / cnt[blk * 2 + 0];
    float invmin = 1.f / cnt[blk * 2 + 1];
    const float invgap = 1.f / (float)HWX;
    float* e = sums + (size_t)blk * EDIM;

    float val[9];
    float sq = 0.f;
    #pragma unroll
    for (int j = 0; j < 9; ++j) {
        int k = t + 256 * j;
        float d = (k < CC) ? invmax : (k < 2 * CC) ? invmin : invgap;
        float v = e[k] * d;
        val[j] = v;
        sq = fmaf(v, v, sq);
    }
    __shared__ float red[256];
    red[t] = sq;
    __syncthreads();
    for (int s = 128; s; s >>= 1) {
        if (t < s) red[t] += red[t + s];
        __syncthreads();
    }
    float rn = 1.f / sqrtf(red[0]);
    #pragma unroll
    for (int j = 0; j < 9; ++j) {
        int k = t + 256 * j;
        float v = val[j] * rn;
        e[k] = v;
        if (img == 1) e2t[(size_t)k * BB + b] = v;
    }
}

// ---------------------------------------------------------------------------
// k5: logits[i][j] = scale * dot(e1[i], e2[j]).  64 blocks x 4 rows each.
__global__ void k5_logits(const float* __restrict__ e, const float* __restrict__ e2t,
                          const float* __restrict__ scale_p, float* __restrict__ logits) {
    int blk = blockIdx.x;            // 0..63 -> rows 4*blk..4*blk+3
    int j = threadIdx.x;             // 0..255
    __shared__ float s1[4][EDIM];
    for (int r = 0; r < 4; ++r)
        for (int k = j; k < EDIM; k += 256)
            s1[r][k] = e[(size_t)(4 * blk + r) * EDIM + k];
    __syncthreads();
    float scale = scale_p[0];
    float a0 = 0.f, a1 = 0.f, a2 = 0.f, a3 = 0.f;
    for (int k = 0; k < EDIM; ++k) {
        float bv = e2t[(size_t)k * BB + j];
        a0 = fmaf(s1[0][k], bv, a0);
        a1 = fmaf(s1[1][k], bv, a1);
        a2 = fmaf(s1[2][k], bv, a2);
        a3 = fmaf(s1[3][k], bv, a3);
    }
    logits[(size_t)(4 * blk + 0) * BB + j] = scale * a0;
    logits[(size_t)(4 * blk + 1) * BB + j] = scale * a1;
    logits[(size_t)(4 * blk + 2) * BB + j] = scale * a2;
    logits[(size_t)(4 * blk + 3) * BB + j] = scale * a3;
}

// ---------------------------------------------------------------------------
// k6: loss = mean_i [ (LSE_row_i + LSE_col_i)/2 - diag_i ]
__global__ void k6_loss(const float* __restrict__ logits, float* __restrict__ out) {
    int i = threadIdx.x;             // 0..255
    float rmax = -__builtin_inff(), cmax = -__builtin_inff();
    for (int k = 0; k < BB; ++k) {
        rmax = fmaxf(rmax, logits[(size_t)i * BB + k]);
        cmax = fmaxf(cmax, logits[(size_t)k * BB + i]);
    }
    float rs = 0.f, cs = 0.f;
    for (int k = 0; k < BB; ++k) {
        rs += expf(logits[(size_t)i * BB + k] - rmax);
        cs += expf(logits[(size_t)k * BB + i] - cmax);
    }
    float lser = rmax + logf(rs);
    float lsec = cmax + logf(cs);
    float diag = logits[(size_t)i * BB + i];
    float v = 0.5f * (lser + lsec) - diag;

    __shared__ float red[256];
    red[i] = v;
    __syncthreads();
    for (int s = 128; s; s >>= 1) {
        if (i < s) red[i] += red[i + s];
        __syncthreads();
    }
    if (i == 0) out[0] = red[0] * (1.f / (float)BB);
}

// ---------------------------------------------------------------------------
extern "C" void kernel_launch(void* const* d_in, const int* in_sizes, int n_in,
                              void* d_out, int out_size, void* d_ws, size_t ws_size,
                              hipStream_t stream) {
    const float* f1 = (const float*)d_in[0];
    const float* f2 = (const float*)d_in[1];
    const float* scale_p = (const float*)d_in[2];
    float* out = (float*)d_out;

    float* ws = (float*)d_ws;
    // offsets in floats
    const size_t off_hm     = 0;                         // 512*576
    const size_t off_mmax   = off_hm     + (size_t)NIMG * BB * HWX;
    const size_t off_mmin   = off_mmax   + (size_t)NIMG * BB * HWX;
    const size_t off_cnt    = off_mmin   + (size_t)NIMG * BB * HWX;
    const size_t off_sums   = off_cnt    + (size_t)NIMG * BB * 2;   // 512*2304
    const size_t off_e2t    = off_sums   + (size_t)NIMG * BB * EDIM;
    const size_t off_logits = off_e2t    + (size_t)EDIM * BB;

    float* hm     = ws + off_hm;
    float* mmax   = ws + off_mmax;
    float* mmin   = ws + off_mmin;
    float* cnt    = ws + off_cnt;
    float* sums   = ws + off_sums;    // becomes normalized e in-place
    float* e2t    = ws + off_e2t;
    float* logits = ws + off_logits;

    hipLaunchKernelGGL(k1_hm,    dim3(NIMG * BB), dim3(HWX), 0, stream, f1, f2, hm);
    hipLaunchKernelGGL(k2_mask,  dim3(NIMG * BB), dim3(HWX), 0, stream, hm, mmax, mmin, cnt);
    hipLaunchKernelGGL(k3_sums,  dim3(NIMG * BB), dim3(256), 0, stream, f1, f2, mmax, mmin, sums);
    hipLaunchKernelGGL(k4_norm,  dim3(NIMG * BB), dim3(256), 0, stream, sums, cnt, e2t);
    hipLaunchKernelGGL(k5_logits, dim3(64),       dim3(256), 0, stream, sums, e2t, scale_p, logits);
    hipLaunchKernelGGL(k6_loss,  dim3(1),         dim3(256), 0, stream, logits, out);
}

// Round 2
// 1094.274 us; speedup vs baseline: 1.1032x; 1.1032x over previous
//
#include <hip/hip_runtime.h>
#include <math.h>

#define BB   256
#define CC   768
#define HHX  24
#define WWX  24
#define HWX  576      // H*W
#define HW4  144      // H*W/4
#define EDIM 2304     // 3*C
#define NIMG 2

// ---------------------------------------------------------------------------
// k1: per-(img,b) channel-sum heatmap, float4 loads.
// thread t: pos4 = t%144, cgroup = t/144; sums channels c ≡ cgroup (mod 4).
__global__ void k1_hm(const float* __restrict__ f1, const float* __restrict__ f2,
                      float* __restrict__ hm) {
    int blk = blockIdx.x;            // 0..511  (img*256 + b)
    int img = blk >> 8;
    int b   = blk & 255;
    const float* base = ((img == 0) ? f1 : f2) + (size_t)b * CC * HWX;
    const float4* base4 = (const float4*)base;
    int t = threadIdx.x;             // 0..575
    int pos4 = t % HW4;
    int cg   = t / HW4;              // 0..3
    float4 acc = make_float4(0.f, 0.f, 0.f, 0.f);
    #pragma unroll 8
    for (int c = cg; c < CC; c += 4) {
        float4 v = base4[(size_t)c * HW4 + pos4];
        acc.x += v.x; acc.y += v.y; acc.z += v.z; acc.w += v.w;
    }
    __shared__ float4 part[HWX];
    part[t] = acc;
    __syncthreads();
    if (t < HW4) {
        float4 a = part[t], b4 = part[t + HW4], c4 = part[t + 2 * HW4], d4 = part[t + 3 * HW4];
        float4 s;
        s.x = a.x + b4.x + c4.x + d4.x;
        s.y = a.y + b4.y + c4.y + d4.y;
        s.z = a.z + b4.z + c4.z + d4.z;
        s.w = a.w + b4.w + c4.w + d4.w;
        ((float4*)(hm + (size_t)blk * HWX))[t] = s;
    }
}

// ---------------------------------------------------------------------------
// k3: fused mask computation + pooled sums. Block per (img,b), 512 threads
// (8 waves), wave handles channels c ≡ wv (mod 8). float4 feature loads.
__global__ void k3_sums(const float* __restrict__ f1, const float* __restrict__ f2,
                        const float* __restrict__ hm, float* __restrict__ cnt,
                        float* __restrict__ sums) {
    int blk = blockIdx.x;            // (img,b)
    int img = blk >> 8, b = blk & 255;
    const float* base = ((img == 0) ? f1 : f2) + (size_t)b * CC * HWX;
    int t = threadIdx.x;             // 0..511
    int lane = t & 63;
    int wv   = t >> 6;               // 0..7

    __shared__ __align__(16) float sh[HWX];
    __shared__ __align__(16) float smm[HWX];
    __shared__ __align__(16) float smn[HWX];
    __shared__ int c0, c1;

    sh[t] = hm[(size_t)blk * HWX + t];
    if (t < HWX - 512) sh[512 + t] = hm[(size_t)blk * HWX + 512 + t];
    if (t == 0) { c0 = 0; c1 = 0; }
    __syncthreads();

    // masks for positions p = t (+512)
    for (int p = t; p < HWX; p += 512) {
        int h = p / WWX, w = p % WWX;
        float v = sh[p];
        float mx = -__builtin_inff(), mn = __builtin_inff();
        #pragma unroll
        for (int dh = -1; dh <= 1; ++dh) {
            int hh = h + dh;
            if (hh < 0 || hh >= HHX) continue;
            #pragma unroll
            for (int dw = -1; dw <= 1; ++dw) {
                int ww = w + dw;
                if (ww < 0 || ww >= WWX) continue;
                float u = sh[hh * WWX + ww];
                mx = fmaxf(mx, u);
                mn = fminf(mn, u);
            }
        }
        bool corner = (p == 0) || (p == WWX - 1) || (p == (HHX - 1) * WWX) || (p == HWX - 1);
        bool ismax = (v >= mx) && !corner;
        bool ismin = (v <= mn) && !corner;
        smm[p] = ismax ? 1.f : 0.f;
        smn[p] = ismin ? 1.f : 0.f;
        if (ismax) atomicAdd(&c0, 1);
        if (ismin) atomicAdd(&c1, 1);
    }
    __syncthreads();
    if (t == 0) {
        cnt[blk * 2 + 0] = (float)c0;
        cnt[blk * 2 + 1] = (float)c1;
    }

    // per-lane mask fragments for the vectorized layout:
    //   j0: floats 4*lane..+3, j1: floats 256+4*lane..+3, j2: float 512+lane
    float4 ma0 = ((const float4*)smm)[lane];
    float4 ma1 = ((const float4*)smm)[64 + lane];
    float  ma2 = smm[512 + lane];
    float4 mi0 = ((const float4*)smn)[lane];
    float4 mi1 = ((const float4*)smn)[64 + lane];
    float  mi2 = smn[512 + lane];

    float* out = sums + (size_t)blk * EDIM;

    for (int c = wv; c < CC; c += 8) {
        const float4* p4 = (const float4*)(base + (size_t)c * HWX);
        float4 v0 = p4[lane];
        float4 v1 = p4[64 + lane];
        float  v2 = (base + (size_t)c * HWX)[512 + lane];

        float s0 = v0.x + v0.y + v0.z + v0.w + v1.x + v1.y + v1.z + v1.w + v2;
        float s1 = v0.x * ma0.x + v0.y * ma0.y + v0.z * ma0.z + v0.w * ma0.w;
        s1 = fmaf(v1.x, ma1.x, s1); s1 = fmaf(v1.y, ma1.y, s1);
        s1 = fmaf(v1.z, ma1.z, s1); s1 = fmaf(v1.w, ma1.w, s1);
        s1 = fmaf(v2, ma2, s1);
        float s2 = v0.x * mi0.x + v0.y * mi0.y + v0.z * mi0.z + v0.w * mi0.w;
        s2 = fmaf(v1.x, mi1.x, s2); s2 = fmaf(v1.y, mi1.y, s2);
        s2 = fmaf(v1.z, mi1.z, s2); s2 = fmaf(v1.w, mi1.w, s2);
        s2 = fmaf(v2, mi2, s2);

        #pragma unroll
        for (int off = 32; off; off >>= 1) {
            s0 += __shfl_down(s0, off, 64);
            s1 += __shfl_down(s1, off, 64);
            s2 += __shfl_down(s2, off, 64);
        }
        if (lane == 0) {
            out[c]          = s1;
            out[CC + c]     = s2;
            out[2 * CC + c] = s0;
        }
    }
}

// ---------------------------------------------------------------------------
// k4: divide by counts / HW, L2-normalize each (img,b) row of 2304, and also
// write transposed copy of normalized e2 for coalesced GEMM reads.
__global__ void k4_norm(float* __restrict__ sums, const float* __restrict__ cnt,
                        float* __restrict__ e2t) {
    int blk = blockIdx.x;            // (img,b)
    int img = blk >> 8, b = blk & 255;
    int t = threadIdx.x;             // 0..255
    float invmax = 1.f / cnt[blk * 2 + 0];
    float invmin = 1.f / cnt[blk * 2 + 1];
    const float invgap = 1.f / (float)HWX;
    float* e = sums + (size_t)blk * EDIM;

    float val[9];
    float sq = 0.f;
    #pragma unroll
    for (int j = 0; j < 9; ++j) {
        int k = t + 256 * j;
        float d = (k < CC) ? invmax : (k < 2 * CC) ? invmin : invgap;
        float v = e[k] * d;
        val[j] = v;
        sq = fmaf(v, v, sq);
    }
    __shared__ float red[256];
    red[t] = sq;
    __syncthreads();
    for (int s = 128; s; s >>= 1) {
        if (t < s) red[t] += red[t + s];
        __syncthreads();
    }
    float rn = 1.f / sqrtf(red[0]);
    #pragma unroll
    for (int j = 0; j < 9; ++j) {
        int k = t + 256 * j;
        float v = val[j] * rn;
        e[k] = v;
        if (img == 1) e2t[(size_t)k * BB + b] = v;
    }
}

// ---------------------------------------------------------------------------
// k5: logits[i][j] = scale * dot(e1[i], e2[j]); also writes logitsT.
// 128 blocks x 2 rows each, 256 threads.
__global__ void k5_logits(const float* __restrict__ e, const float* __restrict__ e2t,
                          const float* __restrict__ scale_p, float* __restrict__ logits,
                          float* __restrict__ logitsT) {
    int blk = blockIdx.x;            // 0..127 -> rows 2*blk, 2*blk+1
    int j = threadIdx.x;             // 0..255
    __shared__ float s1[2][EDIM];
    for (int r = 0; r < 2; ++r)
        for (int k = j; k < EDIM; k += 256)
            s1[r][k] = e[(size_t)(2 * blk + r) * EDIM + k];
    __syncthreads();
    float scale = scale_p[0];
    float a0 = 0.f, a1 = 0.f;
    for (int k = 0; k < EDIM; k += 4) {
        float b0 = e2t[(size_t)(k + 0) * BB + j];
        float b1 = e2t[(size_t)(k + 1) * BB + j];
        float b2 = e2t[(size_t)(k + 2) * BB + j];
        float b3 = e2t[(size_t)(k + 3) * BB + j];
        a0 = fmaf(s1[0][k + 0], b0, a0); a1 = fmaf(s1[1][k + 0], b0, a1);
        a0 = fmaf(s1[0][k + 1], b1, a0); a1 = fmaf(s1[1][k + 1], b1, a1);
        a0 = fmaf(s1[0][k + 2], b2, a0); a1 = fmaf(s1[1][k + 2], b2, a1);
        a0 = fmaf(s1[0][k + 3], b3, a0); a1 = fmaf(s1[1][k + 3], b3, a1);
    }
    float r0 = scale * a0, r1 = scale * a1;
    logits[(size_t)(2 * blk + 0) * BB + j] = r0;
    logits[(size_t)(2 * blk + 1) * BB + j] = r1;
    logitsT[(size_t)j * BB + (2 * blk + 0)] = r0;
    logitsT[(size_t)j * BB + (2 * blk + 1)] = r1;
}

// ---------------------------------------------------------------------------
// k6: one wave per LSE. g in [0,512): g<256 -> row g of logits (row LSE),
// else row g-256 of logitsT (col LSE).
__global__ void k6_lse(const float* __restrict__ logits, const float* __restrict__ logitsT,
                       float* __restrict__ lse) {
    int g = blockIdx.x * 4 + (threadIdx.x >> 6);   // 0..511
    int lane = threadIdx.x & 63;
    const float* row = (g < BB) ? (logits + (size_t)g * BB)
                                : (logitsT + (size_t)(g - BB) * BB);
    float4 v = ((const float4*)row)[lane];
    float m = fmaxf(fmaxf(v.x, v.y), fmaxf(v.z, v.w));
    #pragma unroll
    for (int off = 32; off; off >>= 1) m = fmaxf(m, __shfl_xor(m, off, 64));
    float s = expf(v.x - m) + expf(v.y - m) + expf(v.z - m) + expf(v.w - m);
    #pragma unroll
    for (int off = 32; off; off >>= 1) s += __shfl_xor(s, off, 64);
    if (lane == 0) lse[g] = m + logf(s);
}

// ---------------------------------------------------------------------------
// k7: loss = mean_i [ 0.5*(lse_row_i + lse_col_i) - diag_i ]
__global__ void k7_loss(const float* __restrict__ logits, const float* __restrict__ lse,
                        float* __restrict__ out) {
    int i = threadIdx.x;             // 0..255
    float v = 0.5f * (lse[i] + lse[BB + i]) - logits[(size_t)i * BB + i];
    __shared__ float red[256];
    red[i] = v;
    __syncthreads();
    for (int s = 128; s; s >>= 1) {
        if (i < s) red[i] += red[i + s];
        __syncthreads();
    }
    if (i == 0) out[0] = red[0] * (1.f / (float)BB);
}

// ---------------------------------------------------------------------------
extern "C" void kernel_launch(void* const* d_in, const int* in_sizes, int n_in,
                              void* d_out, int out_size, void* d_ws, size_t ws_size,
                              hipStream_t stream) {
    const float* f1 = (const float*)d_in[0];
    const float* f2 = (const float*)d_in[1];
    const float* scale_p = (const float*)d_in[2];
    float* out = (float*)d_out;

    float* ws = (float*)d_ws;
    // offsets in floats
    const size_t off_hm      = 0;                                   // 512*576
    const size_t off_cnt     = off_hm      + (size_t)NIMG * BB * HWX;
    const size_t off_sums    = off_cnt     + (size_t)NIMG * BB * 2; // 512*2304
    const size_t off_e2t     = off_sums    + (size_t)NIMG * BB * EDIM;
    const size_t off_logits  = off_e2t     + (size_t)EDIM * BB;
    const size_t off_logitsT = off_logits  + (size_t)BB * BB;
    const size_t off_lse     = off_logitsT + (size_t)BB * BB;

    float* hm      = ws + off_hm;
    float* cnt     = ws + off_cnt;
    float* sums    = ws + off_sums;   // becomes normalized e in-place
    float* e2t     = ws + off_e2t;
    float* logits  = ws + off_logits;
    float* logitsT = ws + off_logitsT;
    float* lse     = ws + off_lse;

    hipLaunchKernelGGL(k1_hm,     dim3(NIMG * BB), dim3(HWX), 0, stream, f1, f2, hm);
    hipLaunchKernelGGL(k3_sums,   dim3(NIMG * BB), dim3(512), 0, stream, f1, f2, hm, cnt, sums);
    hipLaunchKernelGGL(k4_norm,   dim3(NIMG * BB), dim3(256), 0, stream, sums, cnt, e2t);
    hipLaunchKernelGGL(k5_logits, dim3(128),       dim3(256), 0, stream, sums, e2t, scale_p, logits, logitsT);
    hipLaunchKernelGGL(k6_lse,    dim3(128),       dim3(256), 0, stream, logits, logitsT, lse);
    hipLaunchKernelGGL(k7_loss,   dim3(1),         dim3(256), 0, stream, logits, lse, out);
}